// Round 13
// baseline (155.935 us; speedup 1.0000x reference)
//
#include <hip/hip_runtime.h>

// PBKDF2 toy-HMAC, lane-parallel (u,v), round-13: round-head hoisting.
// Each round's head (w1, g11a, w3, A1) is computed in the PREVIOUS round's
// tail from pre-merge values, eliminating all DPP hazard nops (every DPP
// source is @-3 by construction) and shortening the path by 1 step/round.
//
// State: u[s]=byte s, v[s]=byte 16+s (s=lane&15, replicated across rows).
// absorb: u'=v+p31; v'=u. Dk(w)[s]=w[(s+k)&15] (DPP row_ror).
// Mix round equations = R11/R12 (position-verified, PASSED):
//   t1=A1+g11a; nu1=u^t1 (L1, 0..14); w2=j>=11?v:nu1; A2=D1(nu1); G=D11(w2);
//   Gm=s15?g11a:G; m_=w3^(A2+Gm) (nv@0..13, new-b15@15, garbage@14);
//   u'=le14?nu1:m_; g17c=D1(m_); nv3=v^(g17c+G) (L3 @14,15); v'=le13?m_:nv3.
// NEW hoist identities (verified lane-by-lane):
//   w1' = (11<=s<=14)?nu1:m_   [u'(11..14)=nu1; u'(15)=m_(15); v'(0..10)=m_]
//   w3' = (s==14)?nv3:m_       [u'(15)=m_(15); v'(14)=nv3; v'(<=13)=m_]
//   A1' = (13<=s<=14)?D1(nv3):g17c
//     [A1'=D1(v'): dst<=12 <- v'[1..13]=m_[1..13]=g17c; dst13 <- v'[14]=nv3[14];
//      dst14 <- v'[15]=nv3[15]; dst15 <- v'[0]=m_[0]=g17c[15] (feeds garbage lane)]
// Iteration boundary (post-absorb u_a=vF+p31, v_a=uF):
//   w1_1 = (j>=11?vF:uF) + p31m   (p31m = j>=11?p31:0)
//   w3_1 = (s15?vF:uF)  + p31s    (p31s = s15?p31:0)
//   A1_1 = D1(uF); g11a_1 = D11(w1_1)
//   check: g11a_1[15]=w1_1[10]=uF[10]=v_a[10] = +11 operand of byte 15. OK
// F-accum: Fu/Fv ^= prev block's (uF,vF) placed in MID fill slots (ancient
// operands -> perfect hazard fillers); epilogue adds block 999. 1000 terms.
// All &255 deferred to the end (+, ^, *31 preserve low 8 bits mod 2^32).
// DPP rotate direction runtime-probed (uniform branch).

template<bool FLIP>
__device__ __forceinline__ void run_chain(unsigned &u_, unsigned &v_,
                                          unsigned &Fu, unsigned &Fv,
                                          unsigned p31v, unsigned p31m, unsigned p31s,
                                          bool j_ge11, bool m_le13, bool m_le14,
                                          bool m_s15, bool m_s14, bool m_1114,
                                          bool m_1314)
{
    // primary semantics: row_ror:N => dst s <- src (s-N)&15
    //   D1 : dst<-src(s+1)  => N=15 -> 0x12F ; flipped -> 0x121
    //   D11: dst<-src(s+11) => N=5  -> 0x125 ; flipped -> 0x12B
    constexpr int P1  = FLIP ? 0x121 : 0x12F;
    constexpr int P11 = FLIP ? 0x12B : 0x125;

#define D1(w)  ((unsigned)__builtin_amdgcn_mov_dpp((int)(w), P1,  0xF, 0xF, false))
#define D11(w) ((unsigned)__builtin_amdgcn_mov_dpp((int)(w), P11, 0xF, 0xF, false))
#define SB()   __builtin_amdgcn_sched_barrier(0)

    unsigned u = u_, v = v_;
    unsigned w1h, g11ah, w3h, A1h;
    unsigned uFp = 0u, vFp = 0u;
    Fu = 0u; Fv = 0u;

    // prologue hoists for block 0, round 1 (one-time, spacing relaxed)
    w1h = j_ge11 ? u : v;
    w3h = m_s15 ? u : v;
    A1h = D1(v);
    g11ah = D11(w1h);   // w1h @-3 (w3h, A1h between)

// MID round: 18 real instrs + 1 FILL slot; all DPP sources @-3.
#define MID(FILL)                                               \
  { unsigned t1   = A1h + g11ah;             SB();              \
    unsigned nu1  = u ^ t1;                  SB();              \
    unsigned w2   = j_ge11 ? v : nu1;        SB();              \
    FILL;                                    SB();              \
    unsigned A2   = D1(nu1);                 SB();              \
    unsigned G    = D11(w2);                 SB();              \
    unsigned Gm   = m_s15 ? g11ah : G;       SB();              \
    unsigned t2   = A2 + Gm;                 SB();              \
    unsigned m_   = w3h ^ t2;                SB();              \
    w1h = m_1114 ? nu1 : m_;                 SB();              \
    u   = m_le14 ? nu1 : m_;                 SB();              \
    unsigned g17c = D1(m_);                  SB();              \
    g11ah = D11(w1h);                        SB();              \
    unsigned t3   = g17c + G;                SB();              \
    unsigned nv3  = v ^ t3;                  SB();              \
    unsigned vm   = m_le13 ? m_ : nv3;       SB();              \
    w3h = m_s14 ? nv3 : m_;                  SB();              \
    unsigned D1x  = D1(nv3);                 SB();              \
    A1h = m_1314 ? D1x : g17c;               SB();              \
    v = vm; }

// BOUNDARY round (round 4 of each block): conventional finish + absorb +
// next-block round-1 head prep. 20 real instrs + 2 spacer slots.
#define BOUNDARY                                                \
  { unsigned t1   = A1h + g11ah;             SB();              \
    unsigned nu1  = u ^ t1;                  SB();              \
    unsigned w2   = j_ge11 ? v : nu1;        SB();              \
    ((void)0);                               SB();              \
    unsigned A2   = D1(nu1);                 SB();              \
    unsigned G    = D11(w2);                 SB();              \
    unsigned Gm   = m_s15 ? g11ah : G;       SB();              \
    unsigned t2   = A2 + Gm;                 SB();              \
    unsigned m_   = w3h ^ t2;                SB();              \
    unsigned uF   = m_le14 ? nu1 : m_;       SB();              \
    ((void)0);                               SB();              \
    unsigned g17c = D1(m_);                  SB();              \
    A1h = D1(uF);                            SB();              \
    unsigned t3   = g17c + G;                SB();              \
    unsigned nv3  = v ^ t3;                  SB();              \
    unsigned vF   = m_le13 ? m_ : nv3;       SB();              \
    unsigned cndx = j_ge11 ? vF : uF;        SB();              \
    unsigned w1n  = cndx + p31m;             SB();              \
    unsigned sx   = m_s15 ? vF : uF;         SB();              \
    w3h = sx + p31s;                         SB();              \
    g11ah = D11(w1n);                        SB();              \
    w1h = w1n;                                                  \
    u = vF + p31v;                           SB();              \
    v = uF;                                                     \
    uFp = uF; vFp = vF; }

    #pragma unroll 1
    for (int b = 0; b < 1000; ++b) {
        MID(Fu ^= uFp);
        MID(Fv ^= vFp);
        MID(((void)0));
        BOUNDARY;
    }
    // final block's U
    Fu ^= uFp;
    Fv ^= vFp;

#undef BOUNDARY
#undef MID
#undef SB
#undef D11
#undef D1
}

__global__ void __launch_bounds__(64) Model_62955630625117_kernel(
    const int* __restrict__ pw_g,
    const int* __restrict__ salt_g,
    int* __restrict__ out)
{
    const int lane = (int)threadIdx.x;
    const unsigned s = (unsigned)(lane & 15);

    // loop-invariant lane masks
    const bool j_ge11 = (s >= 11u);
    const bool m_le13 = (s <= 13u);
    const bool m_le14 = (s <= 14u);
    const bool m_s15  = (s == 15u);
    const bool m_s14  = (s == 14u);
    const bool m_1114 = (s >= 11u) & (s <= 14u);
    const bool m_1314 = (s >= 13u) & (s <= 14u);

    // --- probe DPP row_ror direction ---
    // primary: 0x12F => dst s <- src (s+1)&15 => lane0 receives 1
    int q = __builtin_amdgcn_mov_dpp((int)s, 0x12F, 0xF, 0xF, false);
    const bool dppflip = (__builtin_amdgcn_readfirstlane(q) != 1);

    // per-lane constants (same in every 16-lane row)
    const unsigned pwv  = (unsigned)pw_g[s];
    const unsigned p31v = pwv * 31u;
    const unsigned p31m = j_ge11 ? p31v : 0u;
    const unsigned p31s = m_s15  ? p31v : 0u;

    // --- initial state: U0 absorb closed form (pw || salt || {0,0,0,1}) ---
    unsigned u = (s < 4u) ? (p31v + (s == 3u ? 1u : 0u)) : pwv;
    unsigned v = (unsigned)salt_g[s];

    unsigned Fu, Fv;
    if (dppflip) run_chain<true >(u, v, Fu, Fv, p31v, p31m, p31s,
                                  j_ge11, m_le13, m_le14, m_s15, m_s14, m_1114, m_1314);
    else         run_chain<false>(u, v, Fu, Fv, p31v, p31m, p31s,
                                  j_ge11, m_le13, m_le14, m_s15, m_s14, m_1114, m_1314);

    if (lane < 32) out[lane] = (int)((lane < 16 ? Fu : Fv) & 255u);
}

extern "C" void kernel_launch(void* const* d_in, const int* in_sizes, int n_in,
                              void* d_out, int out_size, void* d_ws, size_t ws_size,
                              hipStream_t stream) {
    const int* pw   = (const int*)d_in[0];
    const int* salt = (const int*)d_in[1];
    int* out = (int*)d_out;
    Model_62955630625117_kernel<<<1, 64, 0, stream>>>(pw, salt, out);
}

// Round 14
// 154.104 us; speedup vs baseline: 1.0119x; 1.0119x over previous
//
#include <hip/hip_runtime.h>

// PBKDF2 toy-HMAC, lane-parallel (u,v), round-14: REVERT to R12 structure
// (R13's head-hoisting regressed 138.8 -> 151.4 us) + DPP-arithmetic fusion.
//
// GCNDPPCombine fuses a single-use v_mov_b32_dpp (full masks, undef old) into
// a commutable VOP2 consumer -> v_add_u32_dpp. The three single-use D1 rotates
// are therefore written as one-expression `D1(x) + y`:
//   t1 = D1(v) + g11a ; t2 = D1(nu1) + Gm ; t3 = D1(m_) + G
// 14 logical instrs/round (was 17). Dataflow IDENTICAL to R11/R12 (PASSED).
// Hazard model (R10-R12 calibrated): DPP-routed source written @-1/@-2 costs
// one s_nop instr (slot); @-3+ free. Fused adds' DPP sources: v (ancient),
// nu1 (@-4), m_ (@-2: 1 nop). g11a's src w1 @-2 (1 nop; round 1 filled by F1).
// G's src w2 @-1 (1 s_nop; round 1 gets F2 making it @-2, still 1 nop).
// Expected ~71 slots/iter = 284 cyc ~ 120 us (R12: 83.5 slots, 138.8 us).
//
// State: u[s]=byte s, v[s]=byte 16+s (s=lane&15, replicated across rows).
// absorb: u'=v+p31; v'=u. Dk(w)[s]=w[(s+k)&15] (DPP row_ror).
// Round equations (position-verified in R11, PASSED):
//   w1=j>=11?u:v ; w3=s15?u:v ; g11a=D11(w1) ; t1=D1(v)+g11a ; nu1=u^t1
//   w2=j>=11?v:nu1 ; G=D11(w2) ; Gm=s15?g11a:G ; t2=D1(nu1)+Gm ; m_=w3^t2
//   u'=le14?nu1:m_ ; t3=D1(m_)+G ; nv3=v^t3 ; v'=le13?m_:nv3
// F-accum (R12 scheme, PASSED): Fu=Fv=0; iter k's round-1 fill slots carry
// Fu^=oldu / Fv^=oldv (U_k, ancient operands); epilogue adds U_999.
// All &255 deferred to the end (+, ^, *31 preserve low 8 bits mod 2^32).
// DPP rotate direction runtime-probed (uniform branch, zero per-iter cost).

template<bool FLIP>
__device__ __forceinline__ void run_chain(unsigned &u, unsigned &v,
                                          unsigned &Fu, unsigned &Fv,
                                          unsigned p31v,
                                          bool j_ge11, bool m_le13,
                                          bool m_le14, bool m_s15)
{
    // primary semantics: row_ror:N => dst s <- src (s-N)&15
    //   D1 : dst<-src(s+1)  => N=15 -> 0x12F ; flipped -> 0x121
    //   D11: dst<-src(s+11) => N=5  -> 0x125 ; flipped -> 0x12B
    constexpr int P1  = FLIP ? 0x121 : 0x12F;
    constexpr int P11 = FLIP ? 0x12B : 0x125;

#define D1(w)  ((unsigned)__builtin_amdgcn_mov_dpp((int)(w), P1,  0xF, 0xF, false))
#define D11(w) ((unsigned)__builtin_amdgcn_mov_dpp((int)(w), P11, 0xF, 0xF, false))
#define SB()   __builtin_amdgcn_sched_barrier(0)

// F1/F2: round 1 of each iteration passes the F-xors as hazard-gap fillers;
// other rounds pass nothing (compiler inserts the s_nop instead).
#define MIXROUND(F1, F2)                                           \
  { unsigned w1   = j_ge11 ? u : v;          SB();                 \
    unsigned w3   = m_s15 ? u : v;           SB();                 \
    F1;                                      SB();                 \
    unsigned g11a = D11(w1);                 SB();                 \
    unsigned t1   = D1(v) + g11a;            SB();                 \
    unsigned nu1  = u ^ t1;                  SB();                 \
    unsigned w2   = j_ge11 ? v : nu1;        SB();                 \
    F2;                                      SB();                 \
    unsigned G    = D11(w2);                 SB();                 \
    unsigned Gm   = m_s15 ? g11a : G;        SB();                 \
    unsigned t2   = D1(nu1) + Gm;            SB();                 \
    unsigned m_   = w3 ^ t2;                 SB();                 \
    u = m_le14 ? nu1 : m_;                   SB();                 \
    unsigned t3   = D1(m_) + G;              SB();                 \
    unsigned nv3  = v ^ t3;                  SB();                 \
    v = m_le13 ? m_ : nv3;                   SB();                 \
  }

#define NOP ((void)0)

    // U0 mix (4 rounds; U0 absorb done closed-form by caller)
    MIXROUND(NOP, NOP); MIXROUND(NOP, NOP);
    MIXROUND(NOP, NOP); MIXROUND(NOP, NOP);

    // F re-based at zero; iter k's round-1 fills accumulate U_k; epilogue U_999.
    Fu = 0u; Fv = 0u;

    #pragma unroll 3
    for (int it = 0; it < 999; ++it) {
        unsigned oldu = u, oldv = v;
        u = oldv + p31v;   // absorb add
        v = oldu;          // rename
        SB();
        MIXROUND(Fu ^= oldu, Fv ^= oldv);   // fills carry F ^= U_k
        MIXROUND(NOP, NOP);
        MIXROUND(NOP, NOP);
        MIXROUND(NOP, NOP);
    }
    // final term U_999
    Fu ^= u;
    Fv ^= v;

#undef NOP
#undef MIXROUND
#undef SB
#undef D11
#undef D1
}

__global__ void __launch_bounds__(64) Model_62955630625117_kernel(
    const int* __restrict__ pw_g,
    const int* __restrict__ salt_g,
    int* __restrict__ out)
{
    const int lane = (int)threadIdx.x;
    const unsigned s = (unsigned)(lane & 15);

    // loop-invariant lane masks
    const bool j_ge11 = (s >= 11u);
    const bool m_le13 = (s <= 13u);
    const bool m_le14 = (s <= 14u);
    const bool m_s15  = (s == 15u);

    // --- probe DPP row_ror direction ---
    // primary: 0x12F => dst s <- src (s+1)&15 => lane0 receives 1
    int q = __builtin_amdgcn_mov_dpp((int)s, 0x12F, 0xF, 0xF, false);
    const bool dppflip = (__builtin_amdgcn_readfirstlane(q) != 1);

    // per-lane constants (same in every 16-lane row)
    const unsigned pwv  = (unsigned)pw_g[s];
    const unsigned p31v = pwv * 31u;

    // --- initial state: U0 absorb closed form (pw || salt || {0,0,0,1}) ---
    unsigned u = (s < 4u) ? (p31v + (s == 3u ? 1u : 0u)) : pwv;
    unsigned v = (unsigned)salt_g[s];

    unsigned Fu, Fv;
    if (dppflip) run_chain<true >(u, v, Fu, Fv, p31v, j_ge11, m_le13, m_le14, m_s15);
    else         run_chain<false>(u, v, Fu, Fv, p31v, j_ge11, m_le13, m_le14, m_s15);

    if (lane < 32) out[lane] = (int)((lane < 16 ? Fu : Fv) & 255u);
}

extern "C" void kernel_launch(void* const* d_in, const int* in_sizes, int n_in,
                              void* d_out, int out_size, void* d_ws, size_t ws_size,
                              hipStream_t stream) {
    const int* pw   = (const int*)d_in[0];
    const int* salt = (const int*)d_in[1];
    int* out = (int*)d_out;
    Model_62955630625117_kernel<<<1, 64, 0, stream>>>(pw, salt, out);
}

// Round 15
// 137.804 us; speedup vs baseline: 1.1316x; 1.1183x over previous
//
#include <hip/hip_runtime.h>

// PBKDF2 toy-HMAC, lane-parallel (u,v), round-15: R12 dataflow + w1h hoist.
//
// Slot model (R10-R14 calibrated): time = (instrs + s_nops) * 4 cyc. The
// hazard recognizer inserts s_nops for ANY VGPR input of a DPP instruction
// written @-1/@-2 (compile-time conservative; wasted issue slots at our
// lone-wave cadence). R14's DPP-add fusion FAILED because fused adds put the
// non-DPP operand @-1. R12 = 17 instrs + 3 nops/round = 138.8us.
// This round: produce next round's w1 mid-round via the R13-verified identity
//   w1_next = (11<=s<=14) ? nu1 : m_     [= j>=11 ? u' : v']
// placed right after m_. Effects: (a) next round's g11a = D11(w1h) has an
// ancient source (nop gone); (b) w1h + u-merge space m_ -> g17c (nop gone).
// Rounds 2-4: 18 slots (1 nop, before A2). Round 1 (post-absorb, fresh w1):
// F-xor fills as spacers, all DPPs free, 20 slots. ~76 slots/iter ~ 127us.
//
// State: u[s]=byte s, v[s]=byte 16+s (s=lane&15, replicated across rows).
// absorb: u'=v+p31; v'=u. Dk(w)[s]=w[(s+k)&15] (DPP row_ror).
// Round equations (position-verified R11, PASSED; w1h identity R13, PASSED):
//   w1=j>=11?u:v ; w3=s15?u:v ; g11a=D11(w1) ; A1=D1(v) ; t1=A1+g11a ;
//   nu1=u^t1 (L1, bytes 0-14) ; w2=j>=11?v:nu1 ; A2=D1(nu1) ; G=D11(w2) ;
//   Gm=s15?g11a:G ; t2=A2+Gm ; m_=w3^t2 (b15@15, b16-29@0-13) ;
//   u'=le14?nu1:m_ ; g17c=D1(m_) ; t3=g17c+G ; nv3=v^t3 (b30,31@14,15) ;
//   v'=le13?m_:nv3
// F-accum (R12, PASSED): Fu=Fv=0; iter k round-1 fills carry Fu^=oldu /
// Fv^=oldv (U_k); epilogue adds U_999. 1000 terms total.
// All &255 deferred to the end (+, ^, *31 preserve low 8 bits mod 2^32).
// DPP rotate direction runtime-probed (uniform branch, zero per-iter cost).

template<bool FLIP>
__device__ __forceinline__ void run_chain(unsigned &u, unsigned &v,
                                          unsigned &Fu, unsigned &Fv,
                                          unsigned p31v,
                                          bool j_ge11, bool m_le13,
                                          bool m_le14, bool m_s15, bool m_1114)
{
    // primary semantics: row_ror:N => dst s <- src (s-N)&15
    //   D1 : dst<-src(s+1)  => N=15 -> 0x12F ; flipped -> 0x121
    //   D11: dst<-src(s+11) => N=5  -> 0x125 ; flipped -> 0x12B
    constexpr int P1  = FLIP ? 0x121 : 0x12F;
    constexpr int P11 = FLIP ? 0x12B : 0x125;

#define D1(w)  ((unsigned)__builtin_amdgcn_mov_dpp((int)(w), P1,  0xF, 0xF, false))
#define D11(w) ((unsigned)__builtin_amdgcn_mov_dpp((int)(w), P11, 0xF, 0xF, false))
#define SB()   __builtin_amdgcn_sched_barrier(0)

    unsigned w1h;

// Round 1 of a block: fresh w1 from post-absorb u,v; F1/F2 fills double as
// hazard spacers (g11a: w1@-3 via w3+F1; A2: nu1@-3 via w2+F2); produces w1h.
#define R1(F1x, F2x)                                               \
  { unsigned w1   = j_ge11 ? u : v;          SB();                 \
    unsigned w3   = m_s15 ? u : v;           SB();                 \
    F1x;                                     SB();                 \
    unsigned g11a = D11(w1);                 SB();                 \
    unsigned A1   = D1(v);                   SB();                 \
    unsigned t1   = A1 + g11a;               SB();                 \
    unsigned nu1  = u ^ t1;                  SB();                 \
    unsigned w2   = j_ge11 ? v : nu1;        SB();                 \
    F2x;                                     SB();                 \
    unsigned A2   = D1(nu1);                 SB();                 \
    unsigned G    = D11(w2);                 SB();                 \
    unsigned Gm   = m_s15 ? g11a : G;        SB();                 \
    unsigned t2   = A2 + Gm;                 SB();                 \
    unsigned m_   = w3 ^ t2;                 SB();                 \
    w1h = m_1114 ? nu1 : m_;                 SB();                 \
    u = m_le14 ? nu1 : m_;                   SB();                 \
    unsigned g17c = D1(m_);                  SB();                 \
    unsigned t3   = g17c + G;                SB();                 \
    unsigned nv3  = v ^ t3;                  SB();                 \
    v = m_le13 ? m_ : nv3;                   SB(); }

// Middle rounds: consume w1h (ancient source -> g11a free), produce w1h.
// Only 1 nop (before A2, nu1@-2); g17c free (w1h + u-merge space m_).
#define MIDR                                                       \
  { unsigned w3   = m_s15 ? u : v;           SB();                 \
    unsigned g11a = D11(w1h);                SB();                 \
    unsigned A1   = D1(v);                   SB();                 \
    unsigned t1   = A1 + g11a;               SB();                 \
    unsigned nu1  = u ^ t1;                  SB();                 \
    unsigned w2   = j_ge11 ? v : nu1;        SB();                 \
    unsigned A2   = D1(nu1);                 SB();                 \
    unsigned G    = D11(w2);                 SB();                 \
    unsigned Gm   = m_s15 ? g11a : G;        SB();                 \
    unsigned t2   = A2 + Gm;                 SB();                 \
    unsigned m_   = w3 ^ t2;                 SB();                 \
    w1h = m_1114 ? nu1 : m_;                 SB();                 \
    u = m_le14 ? nu1 : m_;                   SB();                 \
    unsigned g17c = D1(m_);                  SB();                 \
    unsigned t3   = g17c + G;                SB();                 \
    unsigned nv3  = v ^ t3;                  SB();                 \
    v = m_le13 ? m_ : nv3;                   SB(); }

// Last round of a block: no w1h production (next block's R1 makes its own).
#define LASTR                                                      \
  { unsigned w3   = m_s15 ? u : v;           SB();                 \
    unsigned g11a = D11(w1h);                SB();                 \
    unsigned A1   = D1(v);                   SB();                 \
    unsigned t1   = A1 + g11a;               SB();                 \
    unsigned nu1  = u ^ t1;                  SB();                 \
    unsigned w2   = j_ge11 ? v : nu1;        SB();                 \
    unsigned A2   = D1(nu1);                 SB();                 \
    unsigned G    = D11(w2);                 SB();                 \
    unsigned Gm   = m_s15 ? g11a : G;        SB();                 \
    unsigned t2   = A2 + Gm;                 SB();                 \
    unsigned m_   = w3 ^ t2;                 SB();                 \
    u = m_le14 ? nu1 : m_;                   SB();                 \
    unsigned g17c = D1(m_);                  SB();                 \
    unsigned t3   = g17c + G;                SB();                 \
    unsigned nv3  = v ^ t3;                  SB();                 \
    v = m_le13 ? m_ : nv3;                   SB(); }

#define NOP ((void)0)

    // ---- U0 mix (4 rounds; one-time, same block structure, no fills) ----
    R1(NOP, NOP); MIDR; MIDR; LASTR;

    // F re-based at zero; iter k's round-1 fills accumulate U_k; epilogue U_999.
    Fu = 0u; Fv = 0u;

    #pragma unroll 3
    for (int it = 0; it < 999; ++it) {
        unsigned oldu = u, oldv = v;
        u = oldv + p31v;   // absorb add
        v = oldu;          // rename
        SB();
        R1(Fu ^= oldu, Fv ^= oldv);
        MIDR;
        MIDR;
        LASTR;
    }
    // final term U_999
    Fu ^= u;
    Fv ^= v;

#undef NOP
#undef LASTR
#undef MIDR
#undef R1
#undef SB
#undef D11
#undef D1
}

__global__ void __launch_bounds__(64) Model_62955630625117_kernel(
    const int* __restrict__ pw_g,
    const int* __restrict__ salt_g,
    int* __restrict__ out)
{
    const int lane = (int)threadIdx.x;
    const unsigned s = (unsigned)(lane & 15);

    // loop-invariant lane masks
    const bool j_ge11 = (s >= 11u);
    const bool m_le13 = (s <= 13u);
    const bool m_le14 = (s <= 14u);
    const bool m_s15  = (s == 15u);
    const bool m_1114 = (s >= 11u) & (s <= 14u);

    // --- probe DPP row_ror direction ---
    // primary: 0x12F => dst s <- src (s+1)&15 => lane0 receives 1
    int q = __builtin_amdgcn_mov_dpp((int)s, 0x12F, 0xF, 0xF, false);
    const bool dppflip = (__builtin_amdgcn_readfirstlane(q) != 1);

    // per-lane constants (same in every 16-lane row)
    const unsigned pwv  = (unsigned)pw_g[s];
    const unsigned p31v = pwv * 31u;

    // --- initial state: U0 absorb closed form (pw || salt || {0,0,0,1}) ---
    unsigned u = (s < 4u) ? (p31v + (s == 3u ? 1u : 0u)) : pwv;
    unsigned v = (unsigned)salt_g[s];

    unsigned Fu, Fv;
    if (dppflip) run_chain<true >(u, v, Fu, Fv, p31v, j_ge11, m_le13, m_le14, m_s15, m_1114);
    else         run_chain<false>(u, v, Fu, Fv, p31v, j_ge11, m_le13, m_le14, m_s15, m_1114);

    if (lane < 32) out[lane] = (int)((lane < 16 ? Fu : Fv) & 255u);
}

extern "C" void kernel_launch(void* const* d_in, const int* in_sizes, int n_in,
                              void* d_out, int out_size, void* d_ws, size_t ws_size,
                              hipStream_t stream) {
    const int* pw   = (const int*)d_in[0];
    const int* salt = (const int*)d_in[1];
    int* out = (int*)d_out;
    Model_62955630625117_kernel<<<1, 64, 0, stream>>>(pw, salt, out);
}

// Round 16
// 133.880 us; speedup vs baseline: 1.1647x; 1.0293x over previous
//
#include <hip/hip_runtime.h>

// PBKDF2 toy-HMAC, lane-parallel (u,v), round-16: R15 + relaxed LASTR tail.
//
// Slot model (R10-R15 calibrated): time = slots * 4cyc; slots = instrs +
// s_nops; DPP with any VGPR input written @-1/@-2 costs 1 s_nop; @-3 free.
// R15 = 80.6 slots/iter (134.4us). Structural floor of this dataflow = 76
// slots (72 real instrs + 4 gap-deficit; every nop-removal identity costs +1
// instr -- verified across 6 candidate transforms). Remaining addressable:
// ~4 slots of loop-control/back-edge movs that full SB fencing keeps OUT of
// LASTR's two nop gaps. This round: (a) remove SBs from LASTR's tail through
// the absorb + loop edge (one region; dep chain forces order; scheduler can
// sink absorb/F-saves/loop-ctl into gap-Y and m_-gap); (b) unroll 9 (999=9x111).
// R1/MIDR stay fully pinned (proven 0/1-nop schedules).
//
// State: u[s]=byte s, v[s]=byte 16+s (s=lane&15, replicated across rows).
// absorb: u'=v+p31; v'=u. Dk(w)[s]=w[(s+k)&15] (DPP row_ror).
// Round equations (position-verified R11, PASSED; w1h identity R13, PASSED):
//   w1=j>=11?u:v ; w3=s15?u:v ; g11a=D11(w1) ; A1=D1(v) ; t1=A1+g11a ;
//   nu1=u^t1 (L1, bytes 0-14) ; w2=j>=11?v:nu1 ; A2=D1(nu1) ; G=D11(w2) ;
//   Gm=s15?g11a:G ; t2=A2+Gm ; m_=w3^t2 (b15@15, b16-29@0-13) ;
//   u'=le14?nu1:m_ ; g17c=D1(m_) ; t3=g17c+G ; nv3=v^t3 (b30,31@14,15) ;
//   v'=le13?m_:nv3 ;  w1h(next) = (11<=s<=14)?nu1:m_
// F-accum (R12, PASSED): Fu=Fv=0; iter k round-1 fills carry Fu^=oldu /
// Fv^=oldv (U_k); epilogue adds U_999. 1000 terms total.
// All &255 deferred to the end (+, ^, *31 preserve low 8 bits mod 2^32).
// DPP rotate direction runtime-probed (uniform branch, zero per-iter cost).

template<bool FLIP>
__device__ __forceinline__ void run_chain(unsigned &u, unsigned &v,
                                          unsigned &Fu, unsigned &Fv,
                                          unsigned p31v,
                                          bool j_ge11, bool m_le13,
                                          bool m_le14, bool m_s15, bool m_1114)
{
    // primary semantics: row_ror:N => dst s <- src (s-N)&15
    //   D1 : dst<-src(s+1)  => N=15 -> 0x12F ; flipped -> 0x121
    //   D11: dst<-src(s+11) => N=5  -> 0x125 ; flipped -> 0x12B
    constexpr int P1  = FLIP ? 0x121 : 0x12F;
    constexpr int P11 = FLIP ? 0x12B : 0x125;

#define D1(w)  ((unsigned)__builtin_amdgcn_mov_dpp((int)(w), P1,  0xF, 0xF, false))
#define D11(w) ((unsigned)__builtin_amdgcn_mov_dpp((int)(w), P11, 0xF, 0xF, false))
#define SB()   __builtin_amdgcn_sched_barrier(0)

    unsigned w1h;

// Round 1 of a block: fresh w1 from post-absorb u,v; F1/F2 fills double as
// hazard spacers (g11a: w1@-3 via w3+F1; A2: nu1@-3 via w2+F2); produces w1h.
#define R1(F1x, F2x)                                               \
  { unsigned w1   = j_ge11 ? u : v;          SB();                 \
    unsigned w3   = m_s15 ? u : v;           SB();                 \
    F1x;                                     SB();                 \
    unsigned g11a = D11(w1);                 SB();                 \
    unsigned A1   = D1(v);                   SB();                 \
    unsigned t1   = A1 + g11a;               SB();                 \
    unsigned nu1  = u ^ t1;                  SB();                 \
    unsigned w2   = j_ge11 ? v : nu1;        SB();                 \
    F2x;                                     SB();                 \
    unsigned A2   = D1(nu1);                 SB();                 \
    unsigned G    = D11(w2);                 SB();                 \
    unsigned Gm   = m_s15 ? g11a : G;        SB();                 \
    unsigned t2   = A2 + Gm;                 SB();                 \
    unsigned m_   = w3 ^ t2;                 SB();                 \
    w1h = m_1114 ? nu1 : m_;                 SB();                 \
    u = m_le14 ? nu1 : m_;                   SB();                 \
    unsigned g17c = D1(m_);                  SB();                 \
    unsigned t3   = g17c + G;                SB();                 \
    unsigned nv3  = v ^ t3;                  SB();                 \
    v = m_le13 ? m_ : nv3;                   SB(); }

// Middle rounds: consume w1h (ancient source -> g11a free), produce w1h.
// Only 1 nop (before A2, nu1@-2); g17c free (w1h + u-merge space m_).
#define MIDR                                                       \
  { unsigned w3   = m_s15 ? u : v;           SB();                 \
    unsigned g11a = D11(w1h);                SB();                 \
    unsigned A1   = D1(v);                   SB();                 \
    unsigned t1   = A1 + g11a;               SB();                 \
    unsigned nu1  = u ^ t1;                  SB();                 \
    unsigned w2   = j_ge11 ? v : nu1;        SB();                 \
    unsigned A2   = D1(nu1);                 SB();                 \
    unsigned G    = D11(w2);                 SB();                 \
    unsigned Gm   = m_s15 ? g11a : G;        SB();                 \
    unsigned t2   = A2 + Gm;                 SB();                 \
    unsigned m_   = w3 ^ t2;                 SB();                 \
    w1h = m_1114 ? nu1 : m_;                 SB();                 \
    u = m_le14 ? nu1 : m_;                   SB();                 \
    unsigned g17c = D1(m_);                  SB();                 \
    unsigned t3   = g17c + G;                SB();                 \
    unsigned nv3  = v ^ t3;                  SB();                 \
    v = m_le13 ? m_ : nv3;                   SB(); }

// Last round of a block: head pinned (through w2), tail UNFENCED so the
// scheduler can sink absorb / F-saves / loop control into the two hazard
// gaps (nu1->A2 and m_->g17c) instead of s_nops.
#define LASTR                                                      \
  { unsigned w3   = m_s15 ? u : v;           SB();                 \
    unsigned g11a = D11(w1h);                SB();                 \
    unsigned A1   = D1(v);                   SB();                 \
    unsigned t1   = A1 + g11a;               SB();                 \
    unsigned nu1  = u ^ t1;                  SB();                 \
    unsigned w2   = j_ge11 ? v : nu1;                              \
    unsigned A2   = D1(nu1);                                       \
    unsigned G    = D11(w2);                                       \
    unsigned Gm   = m_s15 ? g11a : G;                              \
    unsigned t2   = A2 + Gm;                                       \
    unsigned m_   = w3 ^ t2;                                       \
    u = m_le14 ? nu1 : m_;                                         \
    unsigned g17c = D1(m_);                                        \
    unsigned t3   = g17c + G;                                      \
    unsigned nv3  = v ^ t3;                                        \
    v = m_le13 ? m_ : nv3;                                         \
  }

#define NOP ((void)0)

    // ---- U0 mix (4 rounds; one-time, same block structure, no fills) ----
    R1(NOP, NOP); MIDR; MIDR; LASTR;

    // F re-based at zero; iter k's round-1 fills accumulate U_k; epilogue U_999.
    Fu = 0u; Fv = 0u;

    #pragma unroll 9
    for (int it = 0; it < 999; ++it) {
        unsigned oldu = u, oldv = v;
        u = oldv + p31v;   // absorb add (unfenced: may sink into LASTR gaps)
        v = oldu;          // rename
        R1(Fu ^= oldu, Fv ^= oldv);
        MIDR;
        MIDR;
        LASTR;
    }
    // final term U_999
    Fu ^= u;
    Fv ^= v;

#undef NOP
#undef LASTR
#undef MIDR
#undef R1
#undef SB
#undef D11
#undef D1
}

__global__ void __launch_bounds__(64) Model_62955630625117_kernel(
    const int* __restrict__ pw_g,
    const int* __restrict__ salt_g,
    int* __restrict__ out)
{
    const int lane = (int)threadIdx.x;
    const unsigned s = (unsigned)(lane & 15);

    // loop-invariant lane masks
    const bool j_ge11 = (s >= 11u);
    const bool m_le13 = (s <= 13u);
    const bool m_le14 = (s <= 14u);
    const bool m_s15  = (s == 15u);
    const bool m_1114 = (s >= 11u) & (s <= 14u);

    // --- probe DPP row_ror direction ---
    // primary: 0x12F => dst s <- src (s+1)&15 => lane0 receives 1
    int q = __builtin_amdgcn_mov_dpp((int)s, 0x12F, 0xF, 0xF, false);
    const bool dppflip = (__builtin_amdgcn_readfirstlane(q) != 1);

    // per-lane constants (same in every 16-lane row)
    const unsigned pwv  = (unsigned)pw_g[s];
    const unsigned p31v = pwv * 31u;

    // --- initial state: U0 absorb closed form (pw || salt || {0,0,0,1}) ---
    unsigned u = (s < 4u) ? (p31v + (s == 3u ? 1u : 0u)) : pwv;
    unsigned v = (unsigned)salt_g[s];

    unsigned Fu, Fv;
    if (dppflip) run_chain<true >(u, v, Fu, Fv, p31v, j_ge11, m_le13, m_le14, m_s15, m_1114);
    else         run_chain<false>(u, v, Fu, Fv, p31v, j_ge11, m_le13, m_le14, m_s15, m_1114);

    if (lane < 32) out[lane] = (int)((lane < 16 ? Fu : Fv) & 255u);
}

extern "C" void kernel_launch(void* const* d_in, const int* in_sizes, int n_in,
                              void* d_out, int out_size, void* d_ws, size_t ws_size,
                              hipStream_t stream) {
    const int* pw   = (const int*)d_in[0];
    const int* salt = (const int*)d_in[1];
    int* out = (int*)d_out;
    Model_62955630625117_kernel<<<1, 64, 0, stream>>>(pw, salt, out);
}

// Round 17
// 132.305 us; speedup vs baseline: 1.1786x; 1.0119x over previous
//
#include <hip/hip_runtime.h>

// PBKDF2 toy-HMAC, lane-parallel (u,v), round-17: optimal filler allocation.
//
// Slot model (R10-R16, 5 consecutive correct predictions): time = slots*4cyc;
// slots = instrs + s_nops; DPP with any VGPR input written @-1/@-2 costs one
// s_nop; @-3+ free. R16 = 78.2 slots (130.3us). Gaps needing spacers: 5/iter;
// movable fillers: 2 F-xors + w3. This round reallocates:
//  (a) w3h = (s==14)?nv3:m_  computed in each round's TAIL (R13-verified
//      identity = next round's w3; also spaces next A1=D1(v) to @-3).
//  (b) F-xors split: Fu^=oldu fills R1's A2-gap, Fv^=oldv fills round-2's.
//  (c) round-3: 1 nop; LASTR: 2 gaps, tail unfenced (loop ctl may sink in).
// Budget: 1+20+18+18+18+0.35 ~= 75.4 slots = 302 cyc/iter ~= 125.5us.
//
// State: u[s]=byte s, v[s]=byte 16+s (s=lane&15, replicated across rows).
// absorb: u'=v+p31; v'=u (rename). Dk(w)[s]=w[(s+k)&15] (DPP row_ror).
// Round equations (position-verified R11; w1h/w3h identities R13; PASSED):
//   w1=j>=11?u:v ; w3=s15?u:v ; g11a=D11(w1) ; A1=D1(v) ; t1=A1+g11a ;
//   nu1=u^t1 (bytes 0-14) ; w2=j>=11?v:nu1 ; A2=D1(nu1) ; G=D11(w2) ;
//   Gm=s15?g11a:G ; t2=A2+Gm ; m_=w3^t2 (b15@15, b16-29@0-13) ;
//   u'=le14?nu1:m_ ; g17c=D1(m_) ; t3=g17c+G ; nv3=v^t3 (b30,31@14,15) ;
//   v'=le13?m_:nv3
//   w1h(next w1) = (11<=s<=14)?nu1:m_ ;  w3h(next w3) = (s==14)?nv3:m_
// F-accum: Fu=Fv=0; iter k xors U_{k-1} (oldu/oldv) inside rounds 1-2;
// epilogue xors U_999. 1000 terms total.
// All &255 deferred to the end (+, ^, *31 preserve low 8 bits mod 2^32).
// DPP rotate direction runtime-probed (uniform branch, zero per-iter cost).

template<bool FLIP>
__device__ __forceinline__ void run_chain(unsigned &u, unsigned &v,
                                          unsigned &Fu, unsigned &Fv,
                                          unsigned p31v,
                                          bool j_ge11, bool m_le13,
                                          bool m_le14, bool m_s15,
                                          bool m_s14, bool m_1114)
{
    // primary semantics: row_ror:N => dst s <- src (s-N)&15
    //   D1 : dst<-src(s+1)  => N=15 -> 0x12F ; flipped -> 0x121
    //   D11: dst<-src(s+11) => N=5  -> 0x125 ; flipped -> 0x12B
    constexpr int P1  = FLIP ? 0x121 : 0x12F;
    constexpr int P11 = FLIP ? 0x12B : 0x125;

#define D1(w)  ((unsigned)__builtin_amdgcn_mov_dpp((int)(w), P1,  0xF, 0xF, false))
#define D11(w) ((unsigned)__builtin_amdgcn_mov_dpp((int)(w), P11, 0xF, 0xF, false))
#define SB()   __builtin_amdgcn_sched_barrier(0)

    unsigned w1h, w3h;

// Round 1 of a block: fresh w1/w3 from post-absorb u,v; FILL fills the A2
// gap; produces w1h, w3h for round 2. 20 slots, 0 nops.
#define R1M(FILL)                                                  \
  { unsigned w1   = j_ge11 ? u : v;          SB();                 \
    unsigned w3   = m_s15 ? u : v;           SB();                 \
    unsigned A1   = D1(v);                   SB();                 \
    unsigned g11a = D11(w1);                 SB();                 \
    unsigned t1   = A1 + g11a;               SB();                 \
    unsigned nu1  = u ^ t1;                  SB();                 \
    unsigned w2   = j_ge11 ? v : nu1;        SB();                 \
    FILL;                                    SB();                 \
    unsigned A2   = D1(nu1);                 SB();                 \
    unsigned G    = D11(w2);                 SB();                 \
    unsigned Gm   = m_s15 ? g11a : G;        SB();                 \
    unsigned t2   = A2 + Gm;                 SB();                 \
    unsigned m_   = w3 ^ t2;                 SB();                 \
    w1h = m_1114 ? nu1 : m_;                 SB();                 \
    u = m_le14 ? nu1 : m_;                   SB();                 \
    unsigned g17c = D1(m_);                  SB();                 \
    unsigned t3   = g17c + G;                SB();                 \
    unsigned nv3  = v ^ t3;                  SB();                 \
    v = m_le13 ? m_ : nv3;                   SB();                 \
    w3h = m_s14 ? nv3 : m_;                  SB(); }

// Middle round with filler: consumes w1h/w3h, produces w1h/w3h. 18 slots,
// 0 nops (A1 spaced @-3 by prev tail's vmerge,w3h + g11a; A2/G/g17c @-3).
#define MIDA(FILL)                                                 \
  { unsigned g11a = D11(w1h);                SB();                 \
    unsigned A1   = D1(v);                   SB();                 \
    unsigned t1   = A1 + g11a;               SB();                 \
    unsigned nu1  = u ^ t1;                  SB();                 \
    unsigned w2   = j_ge11 ? v : nu1;        SB();                 \
    FILL;                                    SB();                 \
    unsigned A2   = D1(nu1);                 SB();                 \
    unsigned G    = D11(w2);                 SB();                 \
    unsigned Gm   = m_s15 ? g11a : G;        SB();                 \
    unsigned t2   = A2 + Gm;                 SB();                 \
    unsigned m_   = w3h ^ t2;                SB();                 \
    w1h = m_1114 ? nu1 : m_;                 SB();                 \
    u = m_le14 ? nu1 : m_;                   SB();                 \
    unsigned g17c = D1(m_);                  SB();                 \
    unsigned t3   = g17c + G;                SB();                 \
    unsigned nv3  = v ^ t3;                  SB();                 \
    v = m_le13 ? m_ : nv3;                   SB();                 \
    w3h = m_s14 ? nv3 : m_;                  SB(); }

// Middle round without filler: 1 nop at the A2 gap (hazard recognizer).
#define MIDB                                                       \
  { unsigned g11a = D11(w1h);                SB();                 \
    unsigned A1   = D1(v);                   SB();                 \
    unsigned t1   = A1 + g11a;               SB();                 \
    unsigned nu1  = u ^ t1;                  SB();                 \
    unsigned w2   = j_ge11 ? v : nu1;        SB();                 \
    unsigned A2   = D1(nu1);                 SB();                 \
    unsigned G    = D11(w2);                 SB();                 \
    unsigned Gm   = m_s15 ? g11a : G;        SB();                 \
    unsigned t2   = A2 + Gm;                 SB();                 \
    unsigned m_   = w3h ^ t2;                SB();                 \
    w1h = m_1114 ? nu1 : m_;                 SB();                 \
    u = m_le14 ? nu1 : m_;                   SB();                 \
    unsigned g17c = D1(m_);                  SB();                 \
    unsigned t3   = g17c + G;                SB();                 \
    unsigned nv3  = v ^ t3;                  SB();                 \
    v = m_le13 ? m_ : nv3;                   SB();                 \
    w3h = m_s14 ? nv3 : m_;                  SB(); }

// Last round of a block: head pinned, tail UNFENCED (scheduler may sink loop
// control / back-edge work into the two hazard gaps). No w1h/w3h production.
#define LASTR                                                      \
  { unsigned g11a = D11(w1h);                SB();                 \
    unsigned A1   = D1(v);                   SB();                 \
    unsigned t1   = A1 + g11a;               SB();                 \
    unsigned nu1  = u ^ t1;                  SB();                 \
    unsigned w2   = j_ge11 ? v : nu1;                              \
    unsigned A2   = D1(nu1);                                       \
    unsigned G    = D11(w2);                                       \
    unsigned Gm   = m_s15 ? g11a : G;                              \
    unsigned t2   = A2 + Gm;                                       \
    unsigned m_   = w3h ^ t2;                                      \
    u = m_le14 ? nu1 : m_;                                         \
    unsigned g17c = D1(m_);                                        \
    unsigned t3   = g17c + G;                                      \
    unsigned nv3  = v ^ t3;                                        \
    v = m_le13 ? m_ : nv3;                                         \
  }

#define NOP ((void)0)

    // ---- U0 mix (4 rounds; one-time) ----
    R1M(NOP); MIDA(NOP); MIDB; LASTR;

    // Fu/Fv accumulate U_0..U_998 inside the loop, U_999 in the epilogue.
    Fu = 0u; Fv = 0u;

    #pragma unroll 9
    for (int it = 0; it < 999; ++it) {
        unsigned oldu = u, oldv = v;   // prev block's final state (SSA, free)
        u = oldv + p31v;               // absorb add
        v = oldu;                      // rename (free)
        R1M(Fu ^= oldu);
        MIDA(Fv ^= oldv);
        MIDB;
        LASTR;
    }
    // final term U_999
    Fu ^= u;
    Fv ^= v;

#undef NOP
#undef LASTR
#undef MIDB
#undef MIDA
#undef R1M
#undef SB
#undef D11
#undef D1
}

__global__ void __launch_bounds__(64) Model_62955630625117_kernel(
    const int* __restrict__ pw_g,
    const int* __restrict__ salt_g,
    int* __restrict__ out)
{
    const int lane = (int)threadIdx.x;
    const unsigned s = (unsigned)(lane & 15);

    // loop-invariant lane masks
    const bool j_ge11 = (s >= 11u);
    const bool m_le13 = (s <= 13u);
    const bool m_le14 = (s <= 14u);
    const bool m_s15  = (s == 15u);
    const bool m_s14  = (s == 14u);
    const bool m_1114 = (s >= 11u) & (s <= 14u);

    // --- probe DPP row_ror direction ---
    // primary: 0x12F => dst s <- src (s+1)&15 => lane0 receives 1
    int q = __builtin_amdgcn_mov_dpp((int)s, 0x12F, 0xF, 0xF, false);
    const bool dppflip = (__builtin_amdgcn_readfirstlane(q) != 1);

    // per-lane constants (same in every 16-lane row)
    const unsigned pwv  = (unsigned)pw_g[s];
    const unsigned p31v = pwv * 31u;

    // --- initial state: U0 absorb closed form (pw || salt || {0,0,0,1}) ---
    unsigned u = (s < 4u) ? (p31v + (s == 3u ? 1u : 0u)) : pwv;
    unsigned v = (unsigned)salt_g[s];

    unsigned Fu, Fv;
    if (dppflip) run_chain<true >(u, v, Fu, Fv, p31v, j_ge11, m_le13, m_le14, m_s15, m_s14, m_1114);
    else         run_chain<false>(u, v, Fu, Fv, p31v, j_ge11, m_le13, m_le14, m_s15, m_s14, m_1114);

    if (lane < 32) out[lane] = (int)((lane < 16 ? Fu : Fv) & 255u);
}

extern "C" void kernel_launch(void* const* d_in, const int* in_sizes, int n_in,
                              void* d_out, int out_size, void* d_ws, size_t ws_size,
                              hipStream_t stream) {
    const int* pw   = (const int*)d_in[0];
    const int* salt = (const int*)d_in[1];
    int* out = (int*)d_out;
    Model_62955630625117_kernel<<<1, 64, 0, stream>>>(pw, salt, out);
}